// Round 1
// baseline (185.039 us; speedup 1.0000x reference)
//
#include <hip/hip_runtime.h>

#define BATCH 16
#define SEQ   4096
#define DIM   256
#define HW    64          // height = width = 64
#define NSTEP 10
#define DT    0.3f

// ---------------------------------------------------------------------------
// Kernel 1: projected[b][e][s] = sum_d x[b][s][d] * W[e][d] + bias[e]
// fp32 VALU GEMM, tiles: BM(s)=128, BN(e)=128, BK=32, 256 threads, 8x8 micro.
// LDS float4 chunks XOR-swizzled: phys_chunk = q ^ (row & 7)  -> conflict-free
// fragment reads (2-way max, free per m136).
// ---------------------------------------------------------------------------
__global__ __launch_bounds__(256) void gemm_proj_kernel(
    const float* __restrict__ x, const float* __restrict__ W,
    const float* __restrict__ bias, float* __restrict__ proj) {
  const int sTile = blockIdx.x * 128;
  const int eTile = blockIdx.y * 128;
  const int b     = blockIdx.z;
  const int t  = threadIdx.x;
  const int tx = t & 15;    // s micro index
  const int ty = t >> 4;    // e micro index

  __shared__ float4 Xs[128 * 8];   // [row(s-local)][chunk] swizzled
  __shared__ float4 Ws[128 * 8];   // [row(e-local)][chunk] swizzled

  float acc[8][8];
#pragma unroll
  for (int i = 0; i < 8; i++)
#pragma unroll
    for (int j = 0; j < 8; j++) acc[i][j] = 0.f;

  const float* xb = x + (size_t)b * SEQ * DIM;

  for (int kt = 0; kt < DIM; kt += 32) {
    // ---- stage tiles (coalesced float4 global loads) ----
#pragma unroll
    for (int ld = 0; ld < 4; ld++) {
      int ci  = t + 256 * ld;      // 0..1023
      int row = ci >> 3;           // 0..127
      int q   = ci & 7;            // 0..7
      int p   = q ^ (row & 7);
      float4 vx = *(const float4*)(xb + (size_t)(sTile + row) * DIM + kt + q * 4);
      Xs[row * 8 + p] = vx;
      float4 vw = *(const float4*)(W + (size_t)(eTile + row) * DIM + kt + q * 4);
      Ws[row * 8 + p] = vw;
    }
    __syncthreads();

#pragma unroll
    for (int kc = 0; kc < 8; kc++) {
      float4 aW[8], aX[8];
#pragma unroll
      for (int i = 0; i < 8; i++)
        aW[i] = Ws[(ty + 16 * i) * 8 + (kc ^ (ty & 7))];
#pragma unroll
      for (int j = 0; j < 8; j++)
        aX[j] = Xs[(tx + 16 * j) * 8 + (kc ^ (tx & 7))];
#pragma unroll
      for (int i = 0; i < 8; i++)
#pragma unroll
        for (int j = 0; j < 8; j++) {
          acc[i][j] = fmaf(aW[i].x, aX[j].x, acc[i][j]);
          acc[i][j] = fmaf(aW[i].y, aX[j].y, acc[i][j]);
          acc[i][j] = fmaf(aW[i].z, aX[j].z, acc[i][j]);
          acc[i][j] = fmaf(aW[i].w, aX[j].w, acc[i][j]);
        }
    }
    __syncthreads();
  }

  // ---- epilogue: proj[(b*DIM+e)*SEQ + s] = acc + bias[e] ----
#pragma unroll
  for (int i = 0; i < 8; i++) {
    int e = eTile + ty + 16 * i;
    float bv = bias[e];
    float* orow = proj + ((size_t)(b * DIM + e)) * SEQ + sTile;
#pragma unroll
    for (int j = 0; j < 8; j++) orow[tx + 16 * j] = acc[i][j] + bv;
  }
}

// ---------------------------------------------------------------------------
// Kernel 2: 10 Euler steps of  f += DT*(D*lap(f) + tanh(f) - f)  on each
// 64x64 plane, then spatial mean. One wave per plane; each lane owns an
// 8x8 patch in registers; halos via __shfl (no LDS, no barriers).
// ---------------------------------------------------------------------------
__device__ __forceinline__ float fast_tanh(float v) {
  float a = fminf(fmaxf(v, -15.f), 15.f);
  float t = __builtin_amdgcn_exp2f(a * 2.885390081777927f);  // e^{2a}
  return 1.f - 2.f * __builtin_amdgcn_rcpf(t + 1.f);
}

__global__ __launch_bounds__(256) void evolve_kernel(
    const float* __restrict__ proj, const float* __restrict__ dcoef,
    float* __restrict__ out) {
  const int wid   = threadIdx.x >> 6;
  const int lane  = threadIdx.x & 63;
  const int plane = blockIdx.x * 4 + wid;   // = b*DIM + e
  const int lx = lane & 7;                  // patch col block
  const int ly = lane >> 3;                 // patch row block
  const float D = dcoef[0];

  const float* p = proj + (size_t)plane * (HW * HW);

  float u[8][8], v[8][8];
#pragma unroll
  for (int r = 0; r < 8; r++) {
    float4 v0 = *(const float4*)(p + (ly * 8 + r) * HW + lx * 8);
    float4 v1 = *(const float4*)(p + (ly * 8 + r) * HW + lx * 8 + 4);
    u[r][0] = v0.x; u[r][1] = v0.y; u[r][2] = v0.z; u[r][3] = v0.w;
    u[r][4] = v1.x; u[r][5] = v1.y; u[r][6] = v1.z; u[r][7] = v1.w;
  }

  auto dostep = [&](float (&src)[8][8], float (&dst)[8][8]) {
    float left[8], right[8], top[8], bot[8];
#pragma unroll
    for (int r = 0; r < 8; r++) {
      float lf = __shfl(src[r][7], (lane - 1) & 63);
      float rt = __shfl(src[r][0], (lane + 1) & 63);
      left[r]  = (lx == 0) ? 0.f : lf;
      right[r] = (lx == 7) ? 0.f : rt;
    }
#pragma unroll
    for (int c = 0; c < 8; c++) {
      float tp = __shfl(src[7][c], (lane - 8) & 63);
      float bt = __shfl(src[0][c], (lane + 8) & 63);
      top[c] = (ly == 0) ? 0.f : tp;
      bot[c] = (ly == 7) ? 0.f : bt;
    }
#pragma unroll
    for (int r = 0; r < 8; r++) {
#pragma unroll
      for (int c = 0; c < 8; c++) {
        float up = (r == 0) ? top[c]   : src[r - 1][c];
        float dn = (r == 7) ? bot[c]   : src[r + 1][c];
        float lf = (c == 0) ? left[r]  : src[r][c - 1];
        float rt = (c == 7) ? right[r] : src[r][c + 1];
        float cen = src[r][c];
        float lap = up + dn + lf + rt - 4.f * cen;
        float th  = fast_tanh(cen);
        dst[r][c] = cen + DT * (fmaf(D, lap, th - cen));
      }
    }
  };

  for (int it = 0; it < NSTEP / 2; it++) {
    dostep(u, v);
    dostep(v, u);
  }

  float s = 0.f;
#pragma unroll
  for (int r = 0; r < 8; r++)
#pragma unroll
    for (int c = 0; c < 8; c++) s += u[r][c];
#pragma unroll
  for (int off = 32; off > 0; off >>= 1) s += __shfl_xor(s, off);
  if (lane == 0) out[plane] = s * (1.f / (HW * HW));
}

// ---------------------------------------------------------------------------
extern "C" void kernel_launch(void* const* d_in, const int* in_sizes, int n_in,
                              void* d_out, int out_size, void* d_ws, size_t ws_size,
                              hipStream_t stream) {
  const float* x    = (const float*)d_in[0];
  const float* W    = (const float*)d_in[1];
  const float* bias = (const float*)d_in[2];
  const float* dc   = (const float*)d_in[3];
  float* out  = (float*)d_out;
  float* proj = (float*)d_ws;   // needs BATCH*DIM*SEQ*4 = 64 MB

  dim3 g1(SEQ / 128, DIM / 128, BATCH);
  gemm_proj_kernel<<<g1, 256, 0, stream>>>(x, W, bias, proj);

  evolve_kernel<<<(BATCH * DIM) / 4, 256, 0, stream>>>(proj, dc, out);
}

// Round 3
// 124.244 us; speedup vs baseline: 1.4893x; 1.4893x over previous
//
#include <hip/hip_runtime.h>
#include <stdint.h>

#define BATCH 16
#define SEQ   4096
#define DIM   256
#define HW    64
#define NSTEP 10
#define DT    0.3f

typedef __attribute__((ext_vector_type(8))) short short8;   // 8 bf16 in 4 VGPRs
typedef __attribute__((ext_vector_type(4))) float f32x4;

// round-to-nearest-even fp32 -> bf16 (bits in high 16)
__device__ __forceinline__ float bfhi(float a) {
  uint32_t u = __float_as_uint(a);
  u += 0x7FFFu + ((u >> 16) & 1u);
  return __uint_as_float(u & 0xFFFF0000u);
}
__device__ __forceinline__ uint32_t pack2(float a, float b) {
  uint32_t ua = __float_as_uint(a), ub = __float_as_uint(b);
  ua += 0x7FFFu + ((ua >> 16) & 1u);
  ub += 0x7FFFu + ((ub >> 16) & 1u);
  return (ua >> 16) | (ub & 0xFFFF0000u);
}

// ---------------------------------------------------------------------------
// proj[(b*DIM+e)*SEQ + s] = sum_d x[b,s,d]*W[e,d] + bias[e]
// bf16x3 emulated-fp32 MFMA. Tile 128e x 128s, BK=32, 256 thr (4 waves, each
// 64x64). LDS rows padded to 80 B -> conflict-free b128 frag reads.
// ---------------------------------------------------------------------------
__global__ __launch_bounds__(256) void gemm_proj_mfma(
    const float* __restrict__ x, const float* __restrict__ W,
    const float* __restrict__ bias, float* __restrict__ proj) {
  const int eTile = blockIdx.x * 128;
  const int sTile = blockIdx.y * 128;
  const int b     = blockIdx.z;
  const int t     = threadIdx.x;
  const int lane  = t & 63;
  const int wid   = t >> 6;
  const int wr    = wid >> 1;     // e half (0..1)
  const int wc    = wid & 1;      // s half (0..1)

  __shared__ char lds[4 * 128 * 80];
  char* Whs = lds;
  char* Wls = lds + 10240;
  char* Xhs = lds + 20480;
  char* Xls = lds + 30720;

  const float* xb = x + (size_t)b * SEQ * DIM;

  f32x4 acc[4][4] = {};

  float4 regW[4], regX[4];

#define ISSUE_LOADS(KT)                                                        \
  {                                                                            \
    _Pragma("unroll")                                                          \
    for (int r = 0; r < 4; r++) {                                              \
      int ci = t + 256 * r;                                                    \
      int row = ci >> 3, q = ci & 7;                                           \
      regW[r] = *(const float4*)(W  + (size_t)(eTile + row) * DIM + (KT) + q * 4); \
      regX[r] = *(const float4*)(xb + (size_t)(sTile + row) * DIM + (KT) + q * 4); \
    }                                                                          \
  }

  ISSUE_LOADS(0);

  for (int kt = 0; kt < DIM; kt += 32) {
    __syncthreads();   // previous tile's readers done
    // convert + write LDS (hi/lo bf16)
#pragma unroll
    for (int r = 0; r < 4; r++) {
      int ci = t + 256 * r;
      int row = ci >> 3, q = ci & 7;
      float4 v = regW[r];
      uint2 hi, lo;
      hi.x = pack2(v.x, v.y); hi.y = pack2(v.z, v.w);
      lo.x = pack2(v.x - bfhi(v.x), v.y - bfhi(v.y));
      lo.y = pack2(v.z - bfhi(v.z), v.w - bfhi(v.w));
      *(uint2*)(Whs + row * 80 + q * 8) = hi;
      *(uint2*)(Wls + row * 80 + q * 8) = lo;
      v = regX[r];
      hi.x = pack2(v.x, v.y); hi.y = pack2(v.z, v.w);
      lo.x = pack2(v.x - bfhi(v.x), v.y - bfhi(v.y));
      lo.y = pack2(v.z - bfhi(v.z), v.w - bfhi(v.w));
      *(uint2*)(Xhs + row * 80 + q * 8) = hi;
      *(uint2*)(Xls + row * 80 + q * 8) = lo;
    }
    __syncthreads();

    if (kt + 32 < DIM) ISSUE_LOADS(kt + 32);   // overlap with MFMA below

    const int c16 = (lane >> 4) * 16;
    const int rlo = lane & 15;
    short8 bh[4], bl[4];
#pragma unroll
    for (int j = 0; j < 4; j++) {
      int rowX = wc * 64 + j * 16 + rlo;
      bh[j] = *(const short8*)(Xhs + rowX * 80 + c16);
      bl[j] = *(const short8*)(Xls + rowX * 80 + c16);
    }
#pragma unroll
    for (int i = 0; i < 4; i++) {
      int rowW = wr * 64 + i * 16 + rlo;
      short8 ah = *(const short8*)(Whs + rowW * 80 + c16);
      short8 al = *(const short8*)(Wls + rowW * 80 + c16);
#pragma unroll
      for (int j = 0; j < 4; j++) {
        acc[i][j] = __builtin_amdgcn_mfma_f32_16x16x32_bf16(ah, bh[j], acc[i][j], 0, 0, 0);
        acc[i][j] = __builtin_amdgcn_mfma_f32_16x16x32_bf16(ah, bl[j], acc[i][j], 0, 0, 0);
        acc[i][j] = __builtin_amdgcn_mfma_f32_16x16x32_bf16(al, bh[j], acc[i][j], 0, 0, 0);
      }
    }
  }
#undef ISSUE_LOADS

  // epilogue: D layout col(s)=lane&15, row(e)=(lane>>4)*4+reg
#pragma unroll
  for (int i = 0; i < 4; i++) {
    int e0 = eTile + wr * 64 + i * 16 + (lane >> 4) * 4;
#pragma unroll
    for (int reg = 0; reg < 4; reg++) {
      int e = e0 + reg;
      float bb = bias[e];
      float* orow = proj + ((size_t)(b * DIM + e)) * SEQ + sTile + wc * 64;
#pragma unroll
      for (int j = 0; j < 4; j++)
        orow[j * 16 + (lane & 15)] = acc[i][j][reg] + bb;
    }
  }
}

// ---------------------------------------------------------------------------
// 10 Euler steps + spatial mean. One wave per 64x64 plane; lane owns 8x8
// patch in registers; halos via __shfl.
// ---------------------------------------------------------------------------
__device__ __forceinline__ float tanh_rcp(float c) {
  // tanh(c) = 1 - 2/(exp2(c*2/ln2)+1); exp2 saturates to inf/0 -> +-1 exactly
  float e = __builtin_amdgcn_exp2f(c * 2.885390081777927f);
  return __builtin_amdgcn_rcpf(e + 1.f);   // returns r; tanh = 1 - 2r (folded by caller)
}

__global__ __launch_bounds__(256) void evolve_kernel(
    const float* __restrict__ proj, const float* __restrict__ dcoef,
    float* __restrict__ out) {
  const int wid   = threadIdx.x >> 6;
  const int lane  = threadIdx.x & 63;
  const int plane = blockIdx.x * 4 + wid;   // = b*DIM + e
  const int lx = lane & 7;
  const int ly = lane >> 3;
  const float D  = dcoef[0];
  const float DD = DT * D;                  // coeff of neighbor sum
  const float A  = 1.f - DT - 4.f * DD;     // coeff of center
  // out = A*c + DT*tanh(c) + DD*s4 ; tanh = 1-2r -> A*c + DT + DD*s4 - 2*DT*r

  const float* p = proj + (size_t)plane * (HW * HW);

  float u[8][8], v[8][8];
#pragma unroll
  for (int r = 0; r < 8; r++) {
    float4 v0 = *(const float4*)(p + (ly * 8 + r) * HW + lx * 8);
    float4 v1 = *(const float4*)(p + (ly * 8 + r) * HW + lx * 8 + 4);
    u[r][0] = v0.x; u[r][1] = v0.y; u[r][2] = v0.z; u[r][3] = v0.w;
    u[r][4] = v1.x; u[r][5] = v1.y; u[r][6] = v1.z; u[r][7] = v1.w;
  }

  auto dostep = [&](float (&src)[8][8], float (&dst)[8][8]) {
    float left[8], right[8], top[8], bot[8];
#pragma unroll
    for (int r = 0; r < 8; r++) {
      float lf = __shfl(src[r][7], (lane - 1) & 63);
      float rt = __shfl(src[r][0], (lane + 1) & 63);
      left[r]  = (lx == 0) ? 0.f : lf;
      right[r] = (lx == 7) ? 0.f : rt;
    }
#pragma unroll
    for (int c = 0; c < 8; c++) {
      float tp = __shfl(src[7][c], (lane - 8) & 63);
      float bt = __shfl(src[0][c], (lane + 8) & 63);
      top[c] = (ly == 0) ? 0.f : tp;
      bot[c] = (ly == 7) ? 0.f : bt;
    }
#pragma unroll
    for (int r = 0; r < 8; r++) {
#pragma unroll
      for (int c = 0; c < 8; c++) {
        float up = (r == 0) ? top[c]   : src[r - 1][c];
        float dn = (r == 7) ? bot[c]   : src[r + 1][c];
        float lf = (c == 0) ? left[r]  : src[r][c - 1];
        float rt = (c == 7) ? right[r] : src[r][c + 1];
        float cen = src[r][c];
        float s4  = (up + dn) + (lf + rt);
        float rr  = tanh_rcp(cen);
        float tmp = fmaf(DD, s4, DT);         // DD*s4 + DT
        tmp = fmaf(-2.f * DT, rr, tmp);       // + DT*(1-2r) folded
        dst[r][c] = fmaf(A, cen, tmp);
      }
    }
  };

  for (int it = 0; it < NSTEP / 2; it++) {
    dostep(u, v);
    dostep(v, u);
  }

  float s = 0.f;
#pragma unroll
  for (int r = 0; r < 8; r++)
#pragma unroll
    for (int c = 0; c < 8; c++) s += u[r][c];
#pragma unroll
  for (int off = 32; off > 0; off >>= 1) s += __shfl_xor(s, off);
  if (lane == 0) out[plane] = s * (1.f / (HW * HW));
}

// ---------------------------------------------------------------------------
extern "C" void kernel_launch(void* const* d_in, const int* in_sizes, int n_in,
                              void* d_out, int out_size, void* d_ws, size_t ws_size,
                              hipStream_t stream) {
  const float* x    = (const float*)d_in[0];
  const float* W    = (const float*)d_in[1];
  const float* bias = (const float*)d_in[2];
  const float* dc   = (const float*)d_in[3];
  float* out  = (float*)d_out;
  float* proj = (float*)d_ws;   // BATCH*DIM*SEQ*4 = 64 MB

  dim3 g1(DIM / 128, SEQ / 128, BATCH);   // e-tile fastest: adjacent WGs share x-tile
  gemm_proj_mfma<<<g1, 256, 0, stream>>>(x, W, bias, proj);

  evolve_kernel<<<(BATCH * DIM) / 4, 256, 0, stream>>>(proj, dc, out);
}